// Round 1
// baseline (285.445 us; speedup 1.0000x reference)
//
#include <hip/hip_runtime.h>
#include <math.h>

// out[m, n] = base[n] - pre_cls[n, idx[m]],  base[n] = sum_c softplus(pre_cls[n, c])
// M = N = 8192, C = 80.
// Strategy: precompute D[c][n] = base[n] - pre_cls[n, c] (2.6 MB, L2-resident),
// then out row m is a contiguous copy of D row idx[m]  -> pure HBM-write-bound.

#define CE_C 80

__device__ __forceinline__ float softplus_f(float x) {
    // logaddexp(x, 0) = max(x,0) + log1p(exp(-|x|))
    return fmaxf(x, 0.0f) + log1pf(expf(-fabsf(x)));
}

// One thread per n. Pass 1: base[n]. Pass 2: write D[c*N + n] (coalesced across n).
__global__ void ce_prep(const float* __restrict__ pre, float* __restrict__ D, int N) {
    int n = blockIdx.x * blockDim.x + threadIdx.x;
    if (n >= N) return;
    const float* row = pre + (long)n * CE_C;
    float base = 0.0f;
#pragma unroll
    for (int c = 0; c < CE_C; c += 4) {
        float4 v = *reinterpret_cast<const float4*>(row + c);
        base += softplus_f(v.x);
        base += softplus_f(v.y);
        base += softplus_f(v.z);
        base += softplus_f(v.w);
    }
#pragma unroll 4
    for (int c = 0; c < CE_C; ++c) {
        D[(long)c * N + n] = base - row[c];  // row[c] re-read hits L1
    }
}

// grid (M, N/(4*block)); each thread copies one float4 of D row idx[m] to out row m.
__global__ void ce_gather(const float* __restrict__ D, const int* __restrict__ idx,
                          float* __restrict__ out, int N) {
    int m = blockIdx.x;
    int c = idx[m];                               // wave-uniform -> scalar load
    const float4* src = reinterpret_cast<const float4*>(D + (long)c * N);
    float4* dst = reinterpret_cast<float4*>(out + (long)m * N);
    int i = blockIdx.y * blockDim.x + threadIdx.x;
    dst[i] = src[i];
}

// ---- fallback path (workspace too small for D): base only (32 KB) ----
__global__ void ce_base(const float* __restrict__ pre, float* __restrict__ base, int N) {
    int n = blockIdx.x * blockDim.x + threadIdx.x;
    if (n >= N) return;
    const float* row = pre + (long)n * CE_C;
    float b = 0.0f;
#pragma unroll
    for (int c = 0; c < CE_C; c += 4) {
        float4 v = *reinterpret_cast<const float4*>(row + c);
        b += softplus_f(v.x);
        b += softplus_f(v.y);
        b += softplus_f(v.z);
        b += softplus_f(v.w);
    }
    base[n] = b;
}

__global__ void ce_direct(const float* __restrict__ pre, const float* __restrict__ base,
                          const int* __restrict__ idx, float* __restrict__ out, int N) {
    int m = blockIdx.x;
    int c = idx[m];
    int n0 = (blockIdx.y * blockDim.x + threadIdx.x) * 4;
    if (n0 >= N) return;
    float4 b = *reinterpret_cast<const float4*>(base + n0);
    float4 r;
    r.x = b.x - pre[(long)(n0 + 0) * CE_C + c];
    r.y = b.y - pre[(long)(n0 + 1) * CE_C + c];
    r.z = b.z - pre[(long)(n0 + 2) * CE_C + c];
    r.w = b.w - pre[(long)(n0 + 3) * CE_C + c];
    *reinterpret_cast<float4*>(out + (long)m * N + n0) = r;
}

extern "C" void kernel_launch(void* const* d_in, const int* in_sizes, int n_in,
                              void* d_out, int out_size, void* d_ws, size_t ws_size,
                              hipStream_t stream) {
    const int* idx  = (const int*)d_in[0];     // gt_kind_ind, int32 [M]
    const float* pre = (const float*)d_in[1];  // pre_cls, f32 [N, C]
    float* out = (float*)d_out;                // f32 [M, N]

    const int M = in_sizes[0];
    const int N = in_sizes[1] / CE_C;

    const size_t needD = (size_t)CE_C * (size_t)N * sizeof(float);
    const int block = 256;
    const int chunks = N / (4 * block);        // 8 for N=8192

    if (ws_size >= needD) {
        float* D = (float*)d_ws;
        ce_prep<<<(N + block - 1) / block, block, 0, stream>>>(pre, D, N);
        dim3 grid(M, chunks);
        ce_gather<<<grid, block, 0, stream>>>(D, idx, out, N);
    } else {
        float* base = (float*)d_ws;            // N floats
        ce_base<<<(N + block - 1) / block, block, 0, stream>>>(pre, base, N);
        dim3 grid(M, chunks);
        ce_direct<<<grid, block, 0, stream>>>(pre, base, idx, out, N);
    }
}